// Round 1
// baseline (313.089 us; speedup 1.0000x reference)
//
#include <hip/hip_runtime.h>

#define N_NODES 100000
#define N_EDGES 1600000
#define NBUCK 391   // ceil(N_NODES / 256) buckets of 256 rows
#define NCHUNK 256  // binC chunk-blocks
#define CHUNK 6250  // N_EDGES / NCHUNK exactly
#define LROW 136    // LDS row stride in shorts (272B): optimal bank pattern
#define DCAP 5120   // binD LDS edge capacity (40KB)

typedef float f32x4 __attribute__((ext_vector_type(4)));
typedef _Float16 f16x8 __attribute__((ext_vector_type(8)));
typedef _Float16 h16x2 __attribute__((ext_vector_type(2)));

// fp32 -> f16 bits (RNE). vals in [0,1) give bits <= 0x3BFF (fits 14 bits).
__device__ __forceinline__ unsigned f2h_bits(float f) {
    union { _Float16 h; unsigned short s; } c;
    c.h = (_Float16)f;
    return c.s;
}
__device__ __forceinline__ h16x2 u2h(unsigned u) {
    union { unsigned u; h16x2 h; } c;
    c.u = u;
    return c.h;
}
// pack low/high 16-bit halves of two uints: result low16 = lo's, high16 = hi's
__device__ __forceinline__ unsigned pk16lo(unsigned hi, unsigned lo) {
    return __builtin_amdgcn_perm(hi, lo, 0x05040100u);
}
__device__ __forceinline__ unsigned pk16hi(unsigned hi, unsigned lo) {
    return __builtin_amdgcn_perm(hi, lo, 0x07060302u);
}
__device__ __forceinline__ float fdot2(h16x2 a, h16x2 b, float c) {
#if __has_builtin(__builtin_amdgcn_fdot2)
    return __builtin_amdgcn_fdot2(a, b, c, false);
#else
    return c + (float)a[0] * (float)b[0] + (float)a[1] * (float)b[1];
#endif
}

__device__ __forceinline__ f16x8 pack_h8(float4 a, float4 b) {
    f16x8 r;
    r[0] = (_Float16)a.x; r[1] = (_Float16)a.y;
    r[2] = (_Float16)a.z; r[3] = (_Float16)a.w;
    r[4] = (_Float16)b.x; r[5] = (_Float16)b.y;
    r[6] = (_Float16)b.z; r[7] = (_Float16)b.w;
    return r;
}

// ============ CSR build: bucket binning, zero contended global atomics ======

// Merged: blocks [0,NCHUNK) = per-chunk bucket histogram (binA);
// blocks [NCHUNK, NCHUNK+192) = weight convert+transpose (cvtw3).
__global__ __launch_bounds__(256) void k_prep(const int* __restrict__ row,
                                              int* __restrict__ hmat,
                                              const float* __restrict__ Wa,
                                              const float* __restrict__ Wb,
                                              const float* __restrict__ Wc,
                                              unsigned short* __restrict__ Wta,
                                              unsigned short* __restrict__ Wtb,
                                              unsigned short* __restrict__ Wtc) {
    if (blockIdx.x < NCHUNK) {
        __shared__ int h[NBUCK];
        for (int i = threadIdx.x; i < NBUCK; i += 256) h[i] = 0;
        __syncthreads();
        int s = blockIdx.x * CHUNK, e = s + CHUNK;
        for (int i = s + threadIdx.x; i < e; i += 256)
            atomicAdd(&h[row[i] >> 8], 1);
        __syncthreads();
        for (int b = threadIdx.x; b < NBUCK; b += 256)
            hmat[blockIdx.x * NBUCK + b] = h[b];
    } else {
        int t = (blockIdx.x - NCHUNK) * 256 + threadIdx.x;
        int which = t >> 14;
        int i = t & 16383;
        int n = i & 127, k = i >> 7;
        const float* W = which == 0 ? Wa : which == 1 ? Wb : Wc;
        unsigned short* Wt = which == 0 ? Wta : which == 1 ? Wtb : Wtc;
        Wt[n * 128 + k] = (unsigned short)f2h_bits(W[k * 128 + n]);
    }
}

// Merged: blocks [0,NBUCK) = per-bucket exclusive scan over chunks (bases);
// block NBUCK = bucket totals + exclusive scan -> bstart.
__global__ __launch_bounds__(512) void k_colscanB(const int* __restrict__ hmat,
                                                  int* __restrict__ bases,
                                                  int* __restrict__ bstart) {
    __shared__ int s[512];
    int b = blockIdx.x, t = threadIdx.x;
    if (b < NBUCK) {
        int v = (t < NCHUNK) ? hmat[t * NBUCK + b] : 0;
        s[t] = v;
        __syncthreads();
        for (int off = 1; off < 512; off <<= 1) {
            int x = (t >= off) ? s[t - off] : 0;
            __syncthreads();
            s[t] += x;
            __syncthreads();
        }
        if (t < NCHUNK) bases[t * NBUCK + b] = s[t] - v;
    } else {
        int v = 0;
        if (t < NBUCK) {
            for (int blk = 0; blk < NCHUNK; blk++) v += hmat[blk * NBUCK + t];
        }
        s[t] = v;
        __syncthreads();
        for (int off = 1; off < 512; off <<= 1) {
            int x = (t >= off) ? s[t - off] : 0;
            __syncthreads();
            s[t] += x;
            __syncthreads();
        }
        if (t < NBUCK) bstart[t] = s[t] - v;
        if (t == NBUCK) bstart[NBUCK] = N_EDGES;
    }
}

// Merged fat kernel: blocks [0,NCHUNK) = binC edge grouping (depends on
// colscanB); blocks [NCHUNK, NCHUNK+1563) = GEMM1 H = relu(X@W_in + b_in)
// (depends only on k_prep's Wtin). Independent work, complementary
// bottlenecks (scatter-latency vs stream-BW) -> overlap on the GPU.
// grouped[i] = {col, (row&255)<<14 | f16bits(val)}
__global__ __launch_bounds__(256) void k_binC_gemm(const int* __restrict__ row,
                                                   const int* __restrict__ col,
                                                   const float* __restrict__ vals,
                                                   const int* __restrict__ bstart,
                                                   const int* __restrict__ bases,
                                                   int2* __restrict__ grouped,
                                                   const float* __restrict__ X,
                                                   const unsigned short* __restrict__ Wt,
                                                   const float* __restrict__ bvec,
                                                   unsigned short* __restrict__ H) {
    __shared__ __align__(16) char smraw[64 * LROW * 2];  // 17408B union
    if (blockIdx.x < NCHUNK) {
        // ---- binC: rank-scatter edges into bucket-grouped order ----
        int* cnt = (int*)smraw;                 // NBUCK ints
        int* basl = (int*)(smraw + 1600);       // NBUCK ints: bstart+bases staged
        for (int i = threadIdx.x; i < NBUCK; i += 256) {
            cnt[i] = 0;
            basl[i] = bstart[i] + bases[blockIdx.x * NBUCK + i];
        }
        __syncthreads();
        int s = blockIdx.x * CHUNK, e = s + CHUNK;
        for (int i = s + threadIdx.x; i < e; i += 256) {
            int r = row[i];
            int b = r >> 8;
            int rank = atomicAdd(&cnt[b], 1);
            int pos = basl[b] + rank;
            unsigned hv = f2h_bits(vals[i]);  // <= 0x3BFF for [0,1)
            grouped[pos] = make_int2(col[i], ((r & 255) << 14) | hv);
        }
    } else {
        // ---- GEMM1: H(f16) = relu(X @ W_in + b_in), f16 MFMA ----
        unsigned short* lds = (unsigned short*)smraw;
        int tid = threadIdx.x;
        int lane = tid & 63, wv = tid >> 6;
        int quad = lane >> 4, c16 = lane & 15;

        f16x8 wf[2][4];
        float bb[2];
#pragma unroll
        for (int nt = 0; nt < 2; nt++) {
            int ng = wv * 2 + nt;
            bb[nt] = bvec[ng * 16 + c16];
#pragma unroll
            for (int kc = 0; kc < 4; kc++)
                wf[nt][kc] = *(const f16x8*)&Wt[(ng * 16 + c16) * 128 + kc * 32 + quad * 8];
        }

        int tilebase = (blockIdx.x - NCHUNK) * 64;
        const float4* Xg = (const float4*)X;
#pragma unroll
        for (int i = 0; i < 4; i++) {
            int c = tid + i * 256;
            int r = c >> 4, o = c & 15;
            int grow = tilebase + r;
            float4 f0 = make_float4(0.f, 0.f, 0.f, 0.f), f1 = f0;
            if (grow < N_NODES) {
                f0 = Xg[(size_t)grow * 32 + o * 2];
                f1 = Xg[(size_t)grow * 32 + o * 2 + 1];
            }
            *(f16x8*)&lds[r * LROW + o * 8] = pack_h8(f0, f1);
        }
        __syncthreads();

        f32x4 acc[4][2] = {};
#pragma unroll
        for (int t4 = 0; t4 < 4; t4++) {
#pragma unroll
            for (int kc = 0; kc < 4; kc++) {
                f16x8 af = *(const f16x8*)&lds[(t4 * 16 + c16) * LROW + kc * 32 + quad * 8];
#pragma unroll
                for (int nt = 0; nt < 2; nt++)
                    acc[t4][nt] = __builtin_amdgcn_mfma_f32_16x16x32_f16(af, wf[nt][kc],
                                                                        acc[t4][nt], 0, 0, 0);
            }
        }
        __syncthreads();

#pragma unroll
        for (int t4 = 0; t4 < 4; t4++)
#pragma unroll
            for (int nt = 0; nt < 2; nt++) {
                int ncol = (wv * 2 + nt) * 16 + c16;
#pragma unroll
                for (int r = 0; r < 4; r++) {
                    float v = fmaxf(acc[t4][nt][r] + bb[nt], 0.f);
                    lds[(t4 * 16 + quad * 4 + r) * LROW + ncol] = (unsigned short)f2h_bits(v);
                }
            }
        __syncthreads();
#pragma unroll
        for (int i = 0; i < 4; i++) {
            int c = tid + i * 256;
            int r = c >> 4, o = c & 15;
            int grow = tilebase + r;
            if (grow < N_NODES)
                *(uint4*)&H[(size_t)grow * 128 + o * 8] = *(const uint4*)&lds[r * LROW + o * 8];
        }
    }
}

// Pass D: LDS-staged rank-scatter, 512 threads (391 blocks -> was the
// occupancy floor of the build chain; 2x threads halves serial depth).
// Final edge word = col<<14 | f16bits(val).
__global__ __launch_bounds__(512) void k_binD(const int2* __restrict__ grouped,
                                              const int* __restrict__ bstart,
                                              unsigned* __restrict__ evf,
                                              int* __restrict__ row_ptr) {
    __shared__ int h[256], sc[256], cur[256];
    __shared__ int2 ebuf[DCAP];
    int b = blockIdx.x, t = threadIdx.x;
    int s0 = bstart[b], e0 = bstart[b + 1];
    int n = e0 - s0;
    bool inlds = (n <= DCAP);
    if (t < 256) h[t] = 0;
    __syncthreads();
    if (inlds) {
        for (int i = t; i < n; i += 512) ebuf[i] = grouped[s0 + i];
        __syncthreads();
        for (int i = t; i < n; i += 512)
            atomicAdd(&h[(ebuf[i].y >> 14) & 255], 1);
    } else {
        for (int i = s0 + t; i < e0; i += 512)
            atomicAdd(&h[(grouped[i].y >> 14) & 255], 1);
    }
    __syncthreads();
    int v = 0;
    if (t < 256) {
        v = h[t];
        sc[t] = v;
    }
    __syncthreads();
    for (int off = 1; off < 256; off <<= 1) {
        int x = (t >= off && t < 256) ? sc[t - off] : 0;
        __syncthreads();
        if (t < 256) sc[t] += x;
        __syncthreads();
    }
    if (t < 256) {
        int excl = sc[t] - v;
        cur[t] = excl;
        int grow = b * 256 + t;
        if (grow <= N_NODES) row_ptr[grow] = s0 + excl;
    }
    __syncthreads();
    if (inlds) {
        for (int i = t; i < n; i += 512) {
            int2 g = ebuf[i];
            int rl = (g.y >> 14) & 255;
            int p = atomicAdd(&cur[rl], 1);
            evf[s0 + p] = ((unsigned)g.x << 14) | (unsigned)(g.y & 0x3fff);
        }
    } else {
        for (int i = s0 + t; i < e0; i += 512) {
            int2 g = grouped[i];
            int rl = (g.y >> 14) & 255;
            int p = atomicAdd(&cur[rl], 1);
            evf[s0 + p] = ((unsigned)g.x << 14) | (unsigned)(g.y & 0x3fff);
        }
    }
}

// ------- SpMM: QUARTER-wave per row (4 rows/wave). Each 16-lane quarter owns
// one row: lane l16 holds dims [l16*8, l16*8+8) across 8 fp32 accumulators.
// Per inner round the quarter processes 4 edges (4 uint4 H-loads in flight per
// wave-instr, same MLP/coalescing as before) via v_dot2_f32_f16 pairs.
// vs wave-per-row: NO 16x shfl_xor reduce epilogue, 4x fewer waves, all 64
// lanes store (1KB contiguous per wave). Gather traffic identical.
__global__ __launch_bounds__(256) void k_spmm(const int* __restrict__ rp,
                                              const unsigned* __restrict__ evf,
                                              const unsigned* __restrict__ Hin,
                                              unsigned* __restrict__ Ho) {
    int tid = threadIdx.x;
    int lane = tid & 63;
    int q = lane >> 4, l16 = lane & 15;
    int wid = (blockIdx.x * 256 + tid) >> 6;
    int r0 = wid * 4 + q;  // grid = N_NODES/16 blocks: covers rows exactly
    int s = rp[r0];
    int e = rp[r0 + 1];
    float a0 = 0.f, a1 = 0.f, a2 = 0.f, a3 = 0.f;
    float a4 = 0.f, a5 = 0.f, a6 = 0.f, a7 = 0.f;
    for (int base = s; base < e; base += 16) {
        int cnt = e - base;
        if (cnt > 16) cnt = 16;
        unsigned ev = evf[base + (l16 < cnt ? l16 : cnt - 1)];
        for (int i = 0; i < cnt; i += 4) {
            int i1 = i + 1, i2 = i + 2, i3 = i + 3;
            unsigned u0 = __shfl(ev, (q << 4) + i, 64);
            unsigned u1 = __shfl(ev, (q << 4) + (i1 < cnt ? i1 : cnt - 1), 64);
            unsigned u2 = __shfl(ev, (q << 4) + (i2 < cnt ? i2 : cnt - 1), 64);
            unsigned u3 = __shfl(ev, (q << 4) + (i3 < cnt ? i3 : cnt - 1), 64);
            const uint4 h0 = *(const uint4*)&Hin[(size_t)(u0 >> 14) * 64 + l16 * 4];
            const uint4 h1 = *(const uint4*)&Hin[(size_t)(u1 >> 14) * 64 + l16 * 4];
            const uint4 h2 = *(const uint4*)&Hin[(size_t)(u2 >> 14) * 64 + l16 * 4];
            const uint4 h3 = *(const uint4*)&Hin[(size_t)(u3 >> 14) * 64 + l16 * 4];
            unsigned m0 = u0 & 0x3fffu;  // i < cnt guaranteed by loop bound
            unsigned m1 = (i1 < cnt) ? (u1 & 0x3fffu) : 0u;
            unsigned m2 = (i2 < cnt) ? (u2 & 0x3fffu) : 0u;
            unsigned m3 = (i3 < cnt) ? (u3 & 0x3fffu) : 0u;
            h16x2 v01 = u2h(pk16lo(m1, m0));
            h16x2 v23 = u2h(pk16lo(m3, m2));
            a0 = fdot2(v01, u2h(pk16lo(h1.x, h0.x)), a0);
            a0 = fdot2(v23, u2h(pk16lo(h3.x, h2.x)), a0);
            a1 = fdot2(v01, u2h(pk16hi(h1.x, h0.x)), a1);
            a1 = fdot2(v23, u2h(pk16hi(h3.x, h2.x)), a1);
            a2 = fdot2(v01, u2h(pk16lo(h1.y, h0.y)), a2);
            a2 = fdot2(v23, u2h(pk16lo(h3.y, h2.y)), a2);
            a3 = fdot2(v01, u2h(pk16hi(h1.y, h0.y)), a3);
            a3 = fdot2(v23, u2h(pk16hi(h3.y, h2.y)), a3);
            a4 = fdot2(v01, u2h(pk16lo(h1.z, h0.z)), a4);
            a4 = fdot2(v23, u2h(pk16lo(h3.z, h2.z)), a4);
            a5 = fdot2(v01, u2h(pk16hi(h1.z, h0.z)), a5);
            a5 = fdot2(v23, u2h(pk16hi(h3.z, h2.z)), a5);
            a6 = fdot2(v01, u2h(pk16lo(h1.w, h0.w)), a6);
            a6 = fdot2(v23, u2h(pk16lo(h3.w, h2.w)), a6);
            a7 = fdot2(v01, u2h(pk16hi(h1.w, h0.w)), a7);
            a7 = fdot2(v23, u2h(pk16hi(h3.w, h2.w)), a7);
        }
    }
    uint4 p;
    p.x = (f2h_bits(a1) << 16) | f2h_bits(a0);
    p.y = (f2h_bits(a3) << 16) | f2h_bits(a2);
    p.z = (f2h_bits(a5) << 16) | f2h_bits(a4);
    p.w = (f2h_bits(a7) << 16) | f2h_bits(a6);
    *(uint4*)&Ho[(size_t)r0 * 64 + l16 * 4] = p;
}

// ------- Final: out = relu(AH@W1 + A2H@W2) @ W_out + b_out, f16 MFMA --------
__global__ __launch_bounds__(256) void k_gemm_out(const unsigned short* __restrict__ AH,
                                                  const unsigned short* __restrict__ A2H,
                                                  const unsigned short* __restrict__ Wt1,
                                                  const unsigned short* __restrict__ Wt2,
                                                  const float* __restrict__ Wout,
                                                  const float* __restrict__ bout,
                                                  float* __restrict__ out) {
    __shared__ unsigned short lds[2][64 * LROW];
    __shared__ float part[4][64];
    int tid = threadIdx.x;
    int lane = tid & 63, wv = tid >> 6;
    int quad = lane >> 4, c16 = lane & 15;

    f16x8 w1f[2][4], w2f[2][4];
    float wo[2];
#pragma unroll
    for (int nt = 0; nt < 2; nt++) {
        int ng = wv * 2 + nt;
        wo[nt] = Wout[ng * 16 + c16];
#pragma unroll
        for (int kc = 0; kc < 4; kc++) {
            w1f[nt][kc] = *(const f16x8*)&Wt1[(ng * 16 + c16) * 128 + kc * 32 + quad * 8];
            w2f[nt][kc] = *(const f16x8*)&Wt2[(ng * 16 + c16) * 128 + kc * 32 + quad * 8];
        }
    }
    float bo = bout[0];

    int tilebase = blockIdx.x * 64;
    const uint4* Ag = (const uint4*)(AH + (size_t)tilebase * 128);
    const uint4* Bg = (const uint4*)(A2H + (size_t)tilebase * 128);
#pragma unroll
    for (int i = 0; i < 4; i++) {
        int c = tid + i * 256;
        int r = c >> 4, o = c & 15;
        *(uint4*)&lds[0][r * LROW + o * 8] = Ag[c];
        *(uint4*)&lds[1][r * LROW + o * 8] = Bg[c];
    }
    __syncthreads();

    f32x4 acc[4][2] = {};
#pragma unroll
    for (int t4 = 0; t4 < 4; t4++) {
#pragma unroll
        for (int kc = 0; kc < 4; kc++) {
            f16x8 afA = *(const f16x8*)&lds[0][(t4 * 16 + c16) * LROW + kc * 32 + quad * 8];
            f16x8 afB = *(const f16x8*)&lds[1][(t4 * 16 + c16) * LROW + kc * 32 + quad * 8];
#pragma unroll
            for (int nt = 0; nt < 2; nt++) {
                acc[t4][nt] = __builtin_amdgcn_mfma_f32_16x16x32_f16(afA, w1f[nt][kc],
                                                                    acc[t4][nt], 0, 0, 0);
                acc[t4][nt] = __builtin_amdgcn_mfma_f32_16x16x32_f16(afB, w2f[nt][kc],
                                                                    acc[t4][nt], 0, 0, 0);
            }
        }
    }

#pragma unroll
    for (int t4 = 0; t4 < 4; t4++) {
        float p[4];
#pragma unroll
        for (int r = 0; r < 4; r++)
            p[r] = fmaxf(acc[t4][0][r], 0.f) * wo[0] + fmaxf(acc[t4][1][r], 0.f) * wo[1];
#pragma unroll
        for (int m = 1; m < 16; m <<= 1)
#pragma unroll
            for (int r = 0; r < 4; r++) p[r] += __shfl_xor(p[r], m, 64);
        if (c16 == 0)
#pragma unroll
            for (int r = 0; r < 4; r++) part[wv][t4 * 16 + quad * 4 + r] = p[r];
    }
    __syncthreads();
    if (tid < 64) {
        int orow = tilebase + tid;
        if (orow < N_NODES)
            out[orow] = part[0][tid] + part[1][tid] + part[2][tid] + part[3][tid] + bo;
    }
}

// ---------------- launch ----------------

extern "C" void kernel_launch(void* const* d_in, const int* in_sizes, int n_in,
                              void* d_out, int out_size, void* d_ws, size_t ws_size,
                              hipStream_t stream) {
    const float* X    = (const float*)d_in[0];
    const int*   row  = (const int*)d_in[1];
    const int*   col  = (const int*)d_in[2];
    const float* vals = (const float*)d_in[3];
    const float* W_in = (const float*)d_in[4];
    const float* b_in = (const float*)d_in[5];
    const float* W1   = (const float*)d_in[6];
    const float* W2   = (const float*)d_in[7];
    const float* Wout = (const float*)d_in[8];
    const float* bout = (const float*)d_in[9];
    float* out = (float*)d_out;

    char* ws = (char*)d_ws;
    size_t off = 0;
    auto alloc = [&](size_t bytes) -> void* {
        void* p = ws + off;
        off += (bytes + 511) & ~(size_t)511;
        return p;
    };
    unsigned short* Hb  = (unsigned short*)alloc((size_t)N_NODES * 128 * 2);  // H f16
    unsigned short* AHb = (unsigned short*)alloc((size_t)N_NODES * 128 * 2);  // AH f16
    unsigned short* A2b = (unsigned short*)alloc((size_t)N_NODES * 128 * 2);  // A2H f16
    unsigned* evf  = (unsigned*)alloc((size_t)N_EDGES * 4);
    int2* grouped  = (int2*)alloc((size_t)N_EDGES * 8);
    unsigned short* Wtin = (unsigned short*)alloc(128 * 128 * 2);
    unsigned short* Wt1  = (unsigned short*)alloc(128 * 128 * 2);
    unsigned short* Wt2  = (unsigned short*)alloc(128 * 128 * 2);
    int*   hmat    = (int*)alloc((size_t)NCHUNK * NBUCK * 4);
    int*   bases   = (int*)alloc((size_t)NCHUNK * NBUCK * 4);
    int*   bstart  = (int*)alloc(512 * 4);
    int*   row_ptr = (int*)alloc((size_t)(N_NODES + 256) * 4);

    int gblk = (N_NODES + 63) / 64;  // 1563

    k_prep<<<NCHUNK + 192, 256, 0, stream>>>(row, hmat, W_in, W1, W2, Wtin, Wt1, Wt2);
    k_colscanB<<<NBUCK + 1, 512, 0, stream>>>(hmat, bases, bstart);
    // binC (blocks 0..255, needs colscanB) overlapped with GEMM1 (needs only
    // k_prep's Wtin) in one fat launch.
    k_binC_gemm<<<NCHUNK + gblk, 256, 0, stream>>>(row, col, vals, bstart, bases,
                                                   grouped, X, Wtin, b_in, Hb);
    k_binD<<<NBUCK, 512, 0, stream>>>(grouped, bstart, evf, row_ptr);

    int sblk = N_NODES / 16;  // 6250 blocks * 16 quarter-waves = 100000 rows exactly
    k_spmm<<<sblk, 256, 0, stream>>>(row_ptr, evf, (const unsigned*)Hb, (unsigned*)AHb);
    k_spmm<<<sblk, 256, 0, stream>>>(row_ptr, evf, (const unsigned*)AHb, (unsigned*)A2b);

    k_gemm_out<<<gblk, 256, 0, stream>>>(AHb, A2b, Wt1, Wt2, Wout, bout, out);
}

// Round 2
// 306.966 us; speedup vs baseline: 1.0199x; 1.0199x over previous
//
#include <hip/hip_runtime.h>

#define N_NODES 100000
#define N_EDGES 1600000
#define NBUCK 391   // ceil(N_NODES / 256) buckets of 256 rows
#define NCHUNK 256  // binC chunk-blocks
#define CHUNK 6250  // N_EDGES / NCHUNK exactly
#define LROW 136    // LDS row stride in shorts (272B): optimal bank pattern
#define DCAP 5120   // binD LDS edge capacity (40KB)

typedef float f32x4 __attribute__((ext_vector_type(4)));
typedef _Float16 f16x8 __attribute__((ext_vector_type(8)));
typedef _Float16 h16x2 __attribute__((ext_vector_type(2)));

// fp32 -> f16 bits (RNE). vals in [0,1) give bits <= 0x3BFF (fits 14 bits).
__device__ __forceinline__ unsigned f2h_bits(float f) {
    union { _Float16 h; unsigned short s; } c;
    c.h = (_Float16)f;
    return c.s;
}
__device__ __forceinline__ h16x2 u2h(unsigned u) {
    union { unsigned u; h16x2 h; } c;
    c.u = u;
    return c.h;
}
// pack low/high 16-bit halves of two uints: result low16 = lo's, high16 = hi's
__device__ __forceinline__ unsigned pk16lo(unsigned hi, unsigned lo) {
    return __builtin_amdgcn_perm(hi, lo, 0x05040100u);
}
__device__ __forceinline__ unsigned pk16hi(unsigned hi, unsigned lo) {
    return __builtin_amdgcn_perm(hi, lo, 0x07060302u);
}
__device__ __forceinline__ float fdot2(h16x2 a, h16x2 b, float c) {
#if __has_builtin(__builtin_amdgcn_fdot2)
    return __builtin_amdgcn_fdot2(a, b, c, false);
#else
    return c + (float)a[0] * (float)b[0] + (float)a[1] * (float)b[1];
#endif
}

__device__ __forceinline__ f16x8 pack_h8(float4 a, float4 b) {
    f16x8 r;
    r[0] = (_Float16)a.x; r[1] = (_Float16)a.y;
    r[2] = (_Float16)a.z; r[3] = (_Float16)a.w;
    r[4] = (_Float16)b.x; r[5] = (_Float16)b.y;
    r[6] = (_Float16)b.z; r[7] = (_Float16)b.w;
    return r;
}

// ============ CSR build: bucket binning, zero contended global atomics ======

// Merged: blocks [0,NCHUNK) = per-chunk bucket histogram (binA);
// blocks [NCHUNK, NCHUNK+192) = weight convert+transpose (cvtw3).
__global__ __launch_bounds__(256) void k_prep(const int* __restrict__ row,
                                              int* __restrict__ hmat,
                                              const float* __restrict__ Wa,
                                              const float* __restrict__ Wb,
                                              const float* __restrict__ Wc,
                                              unsigned short* __restrict__ Wta,
                                              unsigned short* __restrict__ Wtb,
                                              unsigned short* __restrict__ Wtc) {
    if (blockIdx.x < NCHUNK) {
        __shared__ int h[NBUCK];
        for (int i = threadIdx.x; i < NBUCK; i += 256) h[i] = 0;
        __syncthreads();
        int s = blockIdx.x * CHUNK, e = s + CHUNK;
        for (int i = s + threadIdx.x; i < e; i += 256)
            atomicAdd(&h[row[i] >> 8], 1);
        __syncthreads();
        for (int b = threadIdx.x; b < NBUCK; b += 256)
            hmat[blockIdx.x * NBUCK + b] = h[b];
    } else {
        int t = (blockIdx.x - NCHUNK) * 256 + threadIdx.x;
        int which = t >> 14;
        int i = t & 16383;
        int n = i & 127, k = i >> 7;
        const float* W = which == 0 ? Wa : which == 1 ? Wb : Wc;
        unsigned short* Wt = which == 0 ? Wta : which == 1 ? Wtb : Wtc;
        Wt[n * 128 + k] = (unsigned short)f2h_bits(W[k * 128 + n]);
    }
}

// Merged: blocks [0,NBUCK) = per-bucket exclusive scan over chunks (bases);
// block NBUCK = bucket totals + exclusive scan -> bstart.
__global__ __launch_bounds__(512) void k_colscanB(const int* __restrict__ hmat,
                                                  int* __restrict__ bases,
                                                  int* __restrict__ bstart) {
    __shared__ int s[512];
    int b = blockIdx.x, t = threadIdx.x;
    if (b < NBUCK) {
        int v = (t < NCHUNK) ? hmat[t * NBUCK + b] : 0;
        s[t] = v;
        __syncthreads();
        for (int off = 1; off < 512; off <<= 1) {
            int x = (t >= off) ? s[t - off] : 0;
            __syncthreads();
            s[t] += x;
            __syncthreads();
        }
        if (t < NCHUNK) bases[t * NBUCK + b] = s[t] - v;
    } else {
        int v = 0;
        if (t < NBUCK) {
            for (int blk = 0; blk < NCHUNK; blk++) v += hmat[blk * NBUCK + t];
        }
        s[t] = v;
        __syncthreads();
        for (int off = 1; off < 512; off <<= 1) {
            int x = (t >= off) ? s[t - off] : 0;
            __syncthreads();
            s[t] += x;
            __syncthreads();
        }
        if (t < NBUCK) bstart[t] = s[t] - v;
        if (t == NBUCK) bstart[NBUCK] = N_EDGES;
    }
}

// Merged fat kernel: blocks [0,NCHUNK) = binC edge grouping (depends on
// colscanB); blocks [NCHUNK, NCHUNK+1563) = GEMM1 H = relu(X@W_in + b_in)
// (depends only on k_prep's Wtin). Independent work, complementary
// bottlenecks (scatter-latency vs stream-BW) -> overlap on the GPU.
// grouped[i] = {col, (row&255)<<14 | f16bits(val)}
__global__ __launch_bounds__(256) void k_binC_gemm(const int* __restrict__ row,
                                                   const int* __restrict__ col,
                                                   const float* __restrict__ vals,
                                                   const int* __restrict__ bstart,
                                                   const int* __restrict__ bases,
                                                   int2* __restrict__ grouped,
                                                   const float* __restrict__ X,
                                                   const unsigned short* __restrict__ Wt,
                                                   const float* __restrict__ bvec,
                                                   unsigned short* __restrict__ H) {
    __shared__ __align__(16) char smraw[64 * LROW * 2];  // 17408B union
    if (blockIdx.x < NCHUNK) {
        // ---- binC: rank-scatter edges into bucket-grouped order ----
        int* cnt = (int*)smraw;                 // NBUCK ints
        int* basl = (int*)(smraw + 1600);       // NBUCK ints: bstart+bases staged
        for (int i = threadIdx.x; i < NBUCK; i += 256) {
            cnt[i] = 0;
            basl[i] = bstart[i] + bases[blockIdx.x * NBUCK + i];
        }
        __syncthreads();
        int s = blockIdx.x * CHUNK, e = s + CHUNK;
        for (int i = s + threadIdx.x; i < e; i += 256) {
            int r = row[i];
            int b = r >> 8;
            int rank = atomicAdd(&cnt[b], 1);
            int pos = basl[b] + rank;
            unsigned hv = f2h_bits(vals[i]);  // <= 0x3BFF for [0,1)
            grouped[pos] = make_int2(col[i], ((r & 255) << 14) | hv);
        }
    } else {
        // ---- GEMM1: H(f16) = relu(X @ W_in + b_in), f16 MFMA ----
        unsigned short* lds = (unsigned short*)smraw;
        int tid = threadIdx.x;
        int lane = tid & 63, wv = tid >> 6;
        int quad = lane >> 4, c16 = lane & 15;

        f16x8 wf[2][4];
        float bb[2];
#pragma unroll
        for (int nt = 0; nt < 2; nt++) {
            int ng = wv * 2 + nt;
            bb[nt] = bvec[ng * 16 + c16];
#pragma unroll
            for (int kc = 0; kc < 4; kc++)
                wf[nt][kc] = *(const f16x8*)&Wt[(ng * 16 + c16) * 128 + kc * 32 + quad * 8];
        }

        int tilebase = (blockIdx.x - NCHUNK) * 64;
        const float4* Xg = (const float4*)X;
#pragma unroll
        for (int i = 0; i < 4; i++) {
            int c = tid + i * 256;
            int r = c >> 4, o = c & 15;
            int grow = tilebase + r;
            float4 f0 = make_float4(0.f, 0.f, 0.f, 0.f), f1 = f0;
            if (grow < N_NODES) {
                f0 = Xg[(size_t)grow * 32 + o * 2];
                f1 = Xg[(size_t)grow * 32 + o * 2 + 1];
            }
            *(f16x8*)&lds[r * LROW + o * 8] = pack_h8(f0, f1);
        }
        __syncthreads();

        f32x4 acc[4][2] = {};
#pragma unroll
        for (int t4 = 0; t4 < 4; t4++) {
#pragma unroll
            for (int kc = 0; kc < 4; kc++) {
                f16x8 af = *(const f16x8*)&lds[(t4 * 16 + c16) * LROW + kc * 32 + quad * 8];
#pragma unroll
                for (int nt = 0; nt < 2; nt++)
                    acc[t4][nt] = __builtin_amdgcn_mfma_f32_16x16x32_f16(af, wf[nt][kc],
                                                                        acc[t4][nt], 0, 0, 0);
            }
        }
        __syncthreads();

#pragma unroll
        for (int t4 = 0; t4 < 4; t4++)
#pragma unroll
            for (int nt = 0; nt < 2; nt++) {
                int ncol = (wv * 2 + nt) * 16 + c16;
#pragma unroll
                for (int r = 0; r < 4; r++) {
                    float v = fmaxf(acc[t4][nt][r] + bb[nt], 0.f);
                    lds[(t4 * 16 + quad * 4 + r) * LROW + ncol] = (unsigned short)f2h_bits(v);
                }
            }
        __syncthreads();
#pragma unroll
        for (int i = 0; i < 4; i++) {
            int c = tid + i * 256;
            int r = c >> 4, o = c & 15;
            int grow = tilebase + r;
            if (grow < N_NODES)
                *(uint4*)&H[(size_t)grow * 128 + o * 8] = *(const uint4*)&lds[r * LROW + o * 8];
        }
    }
}

// Pass D: LDS-staged rank-scatter, 512 threads.
// Final edge word = col<<14 | f16bits(val).
__global__ __launch_bounds__(512) void k_binD(const int2* __restrict__ grouped,
                                              const int* __restrict__ bstart,
                                              unsigned* __restrict__ evf,
                                              int* __restrict__ row_ptr) {
    __shared__ int h[256], sc[256], cur[256];
    __shared__ int2 ebuf[DCAP];
    int b = blockIdx.x, t = threadIdx.x;
    int s0 = bstart[b], e0 = bstart[b + 1];
    int n = e0 - s0;
    bool inlds = (n <= DCAP);
    if (t < 256) h[t] = 0;
    __syncthreads();
    if (inlds) {
        for (int i = t; i < n; i += 512) ebuf[i] = grouped[s0 + i];
        __syncthreads();
        for (int i = t; i < n; i += 512)
            atomicAdd(&h[(ebuf[i].y >> 14) & 255], 1);
    } else {
        for (int i = s0 + t; i < e0; i += 512)
            atomicAdd(&h[(grouped[i].y >> 14) & 255], 1);
    }
    __syncthreads();
    int v = 0;
    if (t < 256) {
        v = h[t];
        sc[t] = v;
    }
    __syncthreads();
    for (int off = 1; off < 256; off <<= 1) {
        int x = (t >= off && t < 256) ? sc[t - off] : 0;
        __syncthreads();
        if (t < 256) sc[t] += x;
        __syncthreads();
    }
    if (t < 256) {
        int excl = sc[t] - v;
        cur[t] = excl;
        int grow = b * 256 + t;
        if (grow <= N_NODES) row_ptr[grow] = s0 + excl;
    }
    __syncthreads();
    if (inlds) {
        for (int i = t; i < n; i += 512) {
            int2 g = ebuf[i];
            int rl = (g.y >> 14) & 255;
            int p = atomicAdd(&cur[rl], 1);
            evf[s0 + p] = ((unsigned)g.x << 14) | (unsigned)(g.y & 0x3fff);
        }
    } else {
        for (int i = s0 + t; i < e0; i += 512) {
            int2 g = grouped[i];
            int rl = (g.y >> 14) & 255;
            int p = atomicAdd(&cur[rl], 1);
            evf[s0 + p] = ((unsigned)g.x << 14) | (unsigned)(g.y & 0x3fff);
        }
    }
}

// ------- SpMM: wave handles TWO adjacent rows with interleaved 16-edge steps.
// Wave-uniform scalar bounds (readfirstlane; adjacent rows -> sB = eA, 3 rp
// loads). 8 gather loads in flight per joint step (vs 4 for one row) -> 2x
// memory-level parallelism for the latency-bound random H gathers, half the
// waves, half the epilogue total. Clamped duplicate lanes get their f16-val
// bits zeroed ONCE at window load, so the fast unmasked step body is always
// correct (OOB slots contribute exactly 0*H = 0) - no tail path.
#define STEP16(EV, R, A0, A1, A2, A3, A4, A5, A6, A7)                          \
    do {                                                                       \
        unsigned u0 = __shfl(EV, (R) + q, 64);                                 \
        unsigned u1 = __shfl(EV, (R) + 4 + q, 64);                             \
        unsigned u2 = __shfl(EV, (R) + 8 + q, 64);                             \
        unsigned u3 = __shfl(EV, (R) + 12 + q, 64);                            \
        const uint4 h0 = *(const uint4*)&Hin[(size_t)(u0 >> 14) * 64 + l16 * 4]; \
        const uint4 h1 = *(const uint4*)&Hin[(size_t)(u1 >> 14) * 64 + l16 * 4]; \
        const uint4 h2 = *(const uint4*)&Hin[(size_t)(u2 >> 14) * 64 + l16 * 4]; \
        const uint4 h3 = *(const uint4*)&Hin[(size_t)(u3 >> 14) * 64 + l16 * 4]; \
        h16x2 v01 = u2h(pk16lo(u1 & 0x3fffu, u0 & 0x3fffu));                   \
        h16x2 v23 = u2h(pk16lo(u3 & 0x3fffu, u2 & 0x3fffu));                   \
        A0 = fdot2(v01, u2h(pk16lo(h1.x, h0.x)), A0);                          \
        A0 = fdot2(v23, u2h(pk16lo(h3.x, h2.x)), A0);                          \
        A1 = fdot2(v01, u2h(pk16hi(h1.x, h0.x)), A1);                          \
        A1 = fdot2(v23, u2h(pk16hi(h3.x, h2.x)), A1);                          \
        A2 = fdot2(v01, u2h(pk16lo(h1.y, h0.y)), A2);                          \
        A2 = fdot2(v23, u2h(pk16lo(h3.y, h2.y)), A2);                          \
        A3 = fdot2(v01, u2h(pk16hi(h1.y, h0.y)), A3);                          \
        A3 = fdot2(v23, u2h(pk16hi(h3.y, h2.y)), A3);                          \
        A4 = fdot2(v01, u2h(pk16lo(h1.z, h0.z)), A4);                          \
        A4 = fdot2(v23, u2h(pk16lo(h3.z, h2.z)), A4);                          \
        A5 = fdot2(v01, u2h(pk16hi(h1.z, h0.z)), A5);                          \
        A5 = fdot2(v23, u2h(pk16hi(h3.z, h2.z)), A5);                          \
        A6 = fdot2(v01, u2h(pk16lo(h1.w, h0.w)), A6);                          \
        A6 = fdot2(v23, u2h(pk16lo(h3.w, h2.w)), A6);                          \
        A7 = fdot2(v01, u2h(pk16hi(h1.w, h0.w)), A7);                          \
        A7 = fdot2(v23, u2h(pk16hi(h3.w, h2.w)), A7);                          \
    } while (0)

__global__ __launch_bounds__(256) void k_spmm(const int* __restrict__ rp,
                                              const unsigned* __restrict__ evf,
                                              const unsigned* __restrict__ Hin,
                                              unsigned* __restrict__ Ho) {
    int tid = threadIdx.x;
    int lane = tid & 63;
    int q = lane >> 4, l16 = lane & 15;
    int wid = (blockIdx.x * 256 + tid) >> 6;  // 0..49999, rows 2w, 2w+1
    int rA = wid * 2;
    int sA = __builtin_amdgcn_readfirstlane(rp[rA]);
    int eA = __builtin_amdgcn_readfirstlane(rp[rA + 1]);
    int eB = __builtin_amdgcn_readfirstlane(rp[rA + 2]);
    int sB = eA;  // adjacent rows share the boundary
    float aA0 = 0.f, aA1 = 0.f, aA2 = 0.f, aA3 = 0.f;
    float aA4 = 0.f, aA5 = 0.f, aA6 = 0.f, aA7 = 0.f;
    float aB0 = 0.f, aB1 = 0.f, aB2 = 0.f, aB3 = 0.f;
    float aB4 = 0.f, aB5 = 0.f, aB6 = 0.f, aB7 = 0.f;
    int baseA = sA, baseB = sB;
    while (baseA < eA || baseB < eB) {
        int cntA = eA - baseA;
        if (cntA > 64) cntA = 64;
        if (cntA < 0) cntA = 0;
        int cntB = eB - baseB;
        if (cntB > 64) cntB = 64;
        if (cntB < 0) cntB = 0;
        unsigned evA = 0u, evB = 0u;
        if (cntA) {
            evA = evf[baseA + (lane < cntA ? lane : cntA - 1)];
            if (lane >= cntA) evA &= ~0x3fffu;  // zero val bits on clamped dups
        }
        if (cntB) {
            evB = evf[baseB + (lane < cntB ? lane : cntB - 1)];
            if (lane >= cntB) evB &= ~0x3fffu;
        }
        int cm = cntA > cntB ? cntA : cntB;
        for (int r = 0; r < cm; r += 16) {
            if (r < cntA) STEP16(evA, r, aA0, aA1, aA2, aA3, aA4, aA5, aA6, aA7);
            if (r < cntB) STEP16(evB, r, aB0, aB1, aB2, aB3, aB4, aB5, aB6, aB7);
        }
        baseA += cntA;
        baseB += cntB;
    }
    aA0 += __shfl_xor(aA0, 16, 64); aA0 += __shfl_xor(aA0, 32, 64);
    aA1 += __shfl_xor(aA1, 16, 64); aA1 += __shfl_xor(aA1, 32, 64);
    aA2 += __shfl_xor(aA2, 16, 64); aA2 += __shfl_xor(aA2, 32, 64);
    aA3 += __shfl_xor(aA3, 16, 64); aA3 += __shfl_xor(aA3, 32, 64);
    aA4 += __shfl_xor(aA4, 16, 64); aA4 += __shfl_xor(aA4, 32, 64);
    aA5 += __shfl_xor(aA5, 16, 64); aA5 += __shfl_xor(aA5, 32, 64);
    aA6 += __shfl_xor(aA6, 16, 64); aA6 += __shfl_xor(aA6, 32, 64);
    aA7 += __shfl_xor(aA7, 16, 64); aA7 += __shfl_xor(aA7, 32, 64);
    aB0 += __shfl_xor(aB0, 16, 64); aB0 += __shfl_xor(aB0, 32, 64);
    aB1 += __shfl_xor(aB1, 16, 64); aB1 += __shfl_xor(aB1, 32, 64);
    aB2 += __shfl_xor(aB2, 16, 64); aB2 += __shfl_xor(aB2, 32, 64);
    aB3 += __shfl_xor(aB3, 16, 64); aB3 += __shfl_xor(aB3, 32, 64);
    aB4 += __shfl_xor(aB4, 16, 64); aB4 += __shfl_xor(aB4, 32, 64);
    aB5 += __shfl_xor(aB5, 16, 64); aB5 += __shfl_xor(aB5, 32, 64);
    aB6 += __shfl_xor(aB6, 16, 64); aB6 += __shfl_xor(aB6, 32, 64);
    aB7 += __shfl_xor(aB7, 16, 64); aB7 += __shfl_xor(aB7, 32, 64);
    if (q < 2) {
        // quarter 0 stores row rA, quarter 1 stores row rA+1 (one wave-instr,
        // 512B contiguous across the two adjacent rows)
        float r0 = q ? aB0 : aA0, r1 = q ? aB1 : aA1;
        float r2 = q ? aB2 : aA2, r3 = q ? aB3 : aA3;
        float r4 = q ? aB4 : aA4, r5 = q ? aB5 : aA5;
        float r6 = q ? aB6 : aA6, r7 = q ? aB7 : aA7;
        uint4 p;
        p.x = (f2h_bits(r1) << 16) | f2h_bits(r0);
        p.y = (f2h_bits(r3) << 16) | f2h_bits(r2);
        p.z = (f2h_bits(r5) << 16) | f2h_bits(r4);
        p.w = (f2h_bits(r7) << 16) | f2h_bits(r6);
        *(uint4*)&Ho[(size_t)(rA + q) * 64 + l16 * 4] = p;
    }
}

// ------- Final: out = relu(AH@W1 + A2H@W2) @ W_out + b_out, f16 MFMA --------
__global__ __launch_bounds__(256) void k_gemm_out(const unsigned short* __restrict__ AH,
                                                  const unsigned short* __restrict__ A2H,
                                                  const unsigned short* __restrict__ Wt1,
                                                  const unsigned short* __restrict__ Wt2,
                                                  const float* __restrict__ Wout,
                                                  const float* __restrict__ bout,
                                                  float* __restrict__ out) {
    __shared__ unsigned short lds[2][64 * LROW];
    __shared__ float part[4][64];
    int tid = threadIdx.x;
    int lane = tid & 63, wv = tid >> 6;
    int quad = lane >> 4, c16 = lane & 15;

    f16x8 w1f[2][4], w2f[2][4];
    float wo[2];
#pragma unroll
    for (int nt = 0; nt < 2; nt++) {
        int ng = wv * 2 + nt;
        wo[nt] = Wout[ng * 16 + c16];
#pragma unroll
        for (int kc = 0; kc < 4; kc++) {
            w1f[nt][kc] = *(const f16x8*)&Wt1[(ng * 16 + c16) * 128 + kc * 32 + quad * 8];
            w2f[nt][kc] = *(const f16x8*)&Wt2[(ng * 16 + c16) * 128 + kc * 32 + quad * 8];
        }
    }
    float bo = bout[0];

    int tilebase = blockIdx.x * 64;
    const uint4* Ag = (const uint4*)(AH + (size_t)tilebase * 128);
    const uint4* Bg = (const uint4*)(A2H + (size_t)tilebase * 128);
#pragma unroll
    for (int i = 0; i < 4; i++) {
        int c = tid + i * 256;
        int r = c >> 4, o = c & 15;
        *(uint4*)&lds[0][r * LROW + o * 8] = Ag[c];
        *(uint4*)&lds[1][r * LROW + o * 8] = Bg[c];
    }
    __syncthreads();

    f32x4 acc[4][2] = {};
#pragma unroll
    for (int t4 = 0; t4 < 4; t4++) {
#pragma unroll
        for (int kc = 0; kc < 4; kc++) {
            f16x8 afA = *(const f16x8*)&lds[0][(t4 * 16 + c16) * LROW + kc * 32 + quad * 8];
            f16x8 afB = *(const f16x8*)&lds[1][(t4 * 16 + c16) * LROW + kc * 32 + quad * 8];
#pragma unroll
            for (int nt = 0; nt < 2; nt++) {
                acc[t4][nt] = __builtin_amdgcn_mfma_f32_16x16x32_f16(afA, w1f[nt][kc],
                                                                    acc[t4][nt], 0, 0, 0);
                acc[t4][nt] = __builtin_amdgcn_mfma_f32_16x16x32_f16(afB, w2f[nt][kc],
                                                                    acc[t4][nt], 0, 0, 0);
            }
        }
    }

#pragma unroll
    for (int t4 = 0; t4 < 4; t4++) {
        float p[4];
#pragma unroll
        for (int r = 0; r < 4; r++)
            p[r] = fmaxf(acc[t4][0][r], 0.f) * wo[0] + fmaxf(acc[t4][1][r], 0.f) * wo[1];
#pragma unroll
        for (int m = 1; m < 16; m <<= 1)
#pragma unroll
            for (int r = 0; r < 4; r++) p[r] += __shfl_xor(p[r], m, 64);
        if (c16 == 0)
#pragma unroll
            for (int r = 0; r < 4; r++) part[wv][t4 * 16 + quad * 4 + r] = p[r];
    }
    __syncthreads();
    if (tid < 64) {
        int orow = tilebase + tid;
        if (orow < N_NODES)
            out[orow] = part[0][tid] + part[1][tid] + part[2][tid] + part[3][tid] + bo;
    }
}

// ---------------- launch ----------------

extern "C" void kernel_launch(void* const* d_in, const int* in_sizes, int n_in,
                              void* d_out, int out_size, void* d_ws, size_t ws_size,
                              hipStream_t stream) {
    const float* X    = (const float*)d_in[0];
    const int*   row  = (const int*)d_in[1];
    const int*   col  = (const int*)d_in[2];
    const float* vals = (const float*)d_in[3];
    const float* W_in = (const float*)d_in[4];
    const float* b_in = (const float*)d_in[5];
    const float* W1   = (const float*)d_in[6];
    const float* W2   = (const float*)d_in[7];
    const float* Wout = (const float*)d_in[8];
    const float* bout = (const float*)d_in[9];
    float* out = (float*)d_out;

    char* ws = (char*)d_ws;
    size_t off = 0;
    auto alloc = [&](size_t bytes) -> void* {
        void* p = ws + off;
        off += (bytes + 511) & ~(size_t)511;
        return p;
    };
    unsigned short* Hb  = (unsigned short*)alloc((size_t)N_NODES * 128 * 2);  // H f16
    unsigned short* AHb = (unsigned short*)alloc((size_t)N_NODES * 128 * 2);  // AH f16
    unsigned short* A2b = (unsigned short*)alloc((size_t)N_NODES * 128 * 2);  // A2H f16
    unsigned* evf  = (unsigned*)alloc((size_t)N_EDGES * 4);
    int2* grouped  = (int2*)alloc((size_t)N_EDGES * 8);
    unsigned short* Wtin = (unsigned short*)alloc(128 * 128 * 2);
    unsigned short* Wt1  = (unsigned short*)alloc(128 * 128 * 2);
    unsigned short* Wt2  = (unsigned short*)alloc(128 * 128 * 2);
    int*   hmat    = (int*)alloc((size_t)NCHUNK * NBUCK * 4);
    int*   bases   = (int*)alloc((size_t)NCHUNK * NBUCK * 4);
    int*   bstart  = (int*)alloc(512 * 4);
    int*   row_ptr = (int*)alloc((size_t)(N_NODES + 256) * 4);

    int gblk = (N_NODES + 63) / 64;  // 1563

    k_prep<<<NCHUNK + 192, 256, 0, stream>>>(row, hmat, W_in, W1, W2, Wtin, Wt1, Wt2);
    k_colscanB<<<NBUCK + 1, 512, 0, stream>>>(hmat, bases, bstart);
    k_binC_gemm<<<NCHUNK + gblk, 256, 0, stream>>>(row, col, vals, bstart, bases,
                                                   grouped, X, Wtin, b_in, Hb);
    k_binD<<<NBUCK, 512, 0, stream>>>(grouped, bstart, evf, row_ptr);

    int sblk = N_NODES / 8;  // 12500 blocks * 4 waves * 2 rows = 100000 rows
    k_spmm<<<sblk, 256, 0, stream>>>(row_ptr, evf, (const unsigned*)Hb, (unsigned*)AHb);
    k_spmm<<<sblk, 256, 0, stream>>>(row_ptr, evf, (const unsigned*)AHb, (unsigned*)A2b);

    k_gemm_out<<<gblk, 256, 0, stream>>>(AHb, A2b, Wt1, Wt2, Wout, bout, out);
}